// Round 4
// baseline (516.616 us; speedup 1.0000x reference)
//
#include <hip/hip_runtime.h>
#include <math.h>

#define N_PTS 8192
#define B_SZ 4
#define SEED_NUM 409
#define FPS_THREADS 256  // 4 waves, 1 per SIMD
#define LTOT 653  // 65+98+131+163+196
#define N_GROUPS (B_SZ * SEED_NUM)

typedef float f2 __attribute__((ext_vector_type(2)));
typedef float f4 __attribute__((ext_vector_type(4)));

// Exact IEEE f32 squared distance, same op order as the reference:
// ((dx*dx + dy*dy) + dz*dz), no FMA contraction.
__device__ __forceinline__ float sqdist(float ax, float ay, float az,
                                        float bx, float by, float bz) {
  float dx = __fsub_rn(ax, bx);
  float dy = __fsub_rn(ay, by);
  float dz = __fsub_rn(az, bz);
  return __fadd_rn(__fadd_rn(__fmul_rn(dx, dx), __fmul_rn(dy, dy)),
                   __fmul_rn(dz, dz));
}

// Forced packed f32 (CDNA4 has v_pk_add_f32 / v_pk_mul_f32, full rate, exact
// IEEE RN per element; there is NO v_pk_min_f32). Non-volatile, reg-only asm:
// the scheduler may reorder/CSE freely.
__device__ __forceinline__ f2 pk_add(f2 a, f2 b) {
  f2 d;
  asm("v_pk_add_f32 %0, %1, %2" : "=v"(d) : "v"(a), "v"(b));
  return d;
}
__device__ __forceinline__ f2 pk_mul(f2 a, f2 b) {
  f2 d;
  asm("v_pk_mul_f32 %0, %1, %2" : "=v"(d) : "v"(a), "v"(b));
  return d;
}

#define FOR16(M) \
  M(0) M(1) M(2) M(3) M(4) M(5) M(6) M(7) \
  M(8) M(9) M(10) M(11) M(12) M(13) M(14) M(15)

// u64 lane-move via two 32-bit DPP ops (ctrl fields must be constant
// expressions -> template params). shr-stages: bound_ctrl=1 (OOB lanes
// read 0 — harmless for max of non-negative keys). bcast stages keep `old`
// in masked-off rows so the subsequent max is a no-op there.
template <int CTRL>
__device__ __forceinline__ unsigned long long dpp_u64_bc1(
    unsigned long long k) {
  const unsigned lo2 = (unsigned)__builtin_amdgcn_update_dpp(
      0, (int)(unsigned)k, CTRL, 0xf, 0xf, true);
  const unsigned hi2 = (unsigned)__builtin_amdgcn_update_dpp(
      0, (int)(unsigned)(k >> 32), CTRL, 0xf, 0xf, true);
  return ((unsigned long long)hi2 << 32) | lo2;
}
template <int CTRL, int ROW_MASK>
__device__ __forceinline__ unsigned long long dpp_u64_keep(
    unsigned long long k) {
  const unsigned lo2 = (unsigned)__builtin_amdgcn_update_dpp(
      (int)(unsigned)k, (int)(unsigned)k, CTRL, ROW_MASK, 0xf, false);
  const unsigned hi2 = (unsigned)__builtin_amdgcn_update_dpp(
      (int)(unsigned)(k >> 32), (int)(unsigned)(k >> 32), CTRL, ROW_MASK, 0xf,
      false);
  return ((unsigned long long)hi2 << 32) | lo2;
}

// ---------------------------------------------------------------------------
// Kernel 1: farthest point sampling. One block per batch (4 blocks).
// R14: (a) forced v_pk_add/mul_f32 via inline asm for the d2 chain — theory:
// the backend was scalarizing the f2 ops (VGPR=132 = 128 pinned + ~4 temps,
// issue model only closes at scalar rates; R9's "packing neutral" = packing
// never reached codegen). Sub done as x + (-c) with pre-negated center
// (IEEE-identical to x-c). (b) REVERT R13's ulonglong2 tail read (+7 us
// measured regression) to R0's plain serial 4-way max.
// (R13: revert to R10 running argmax — select chain is hidden under issue.
//  R10: 4 waves, 32 pts/thread in f2 pairs, f4 winner broadcast.
//  R8: packed f32. R6: DPP argmax reduce. R4: asm "+v" pin.)
// ---------------------------------------------------------------------------
__global__ __launch_bounds__(FPS_THREADS, 1) void fps_kernel(
    const float* __restrict__ pcs, float* __restrict__ seeds,
    double* __restrict__ sums /*26 doubles: totS[5]+accA[20]+donecnt*/) {
#pragma clang fp contract(off)
  const int b = blockIdx.x;
  const int tid = threadIdx.x;
  const int lane = tid & 63, wid = tid >> 6;  // 4 waves
  const float* base = pcs + (size_t)b * N_PTS * 3;

  if (b == 0 && tid < 26) sums[tid] = 0.0;  // zero totS[5]+accA[20]+donecnt

  __shared__ f4 spts4[N_PTS];              // 128 KiB: winner-coord broadcast
  __shared__ float seedbuf[SEED_NUM * 3];  // 4.8 KiB: deferred seed output
  __shared__ unsigned long long red[2][4];

  // pair j holds points i0 = tid + (2j)*256 and i1 = tid + (2j+1)*256
#define FPS_DECL(j) f2 px##j, py##j, pz##j, md##j;
  FOR16(FPS_DECL)
#undef FPS_DECL

#define FPS_INIT(j)                                   \
  {                                                   \
    const int i0 = tid + (2 * (j)) * FPS_THREADS;     \
    const int i1 = i0 + FPS_THREADS;                  \
    px##j = (f2){base[i0 * 3 + 0], base[i1 * 3 + 0]}; \
    py##j = (f2){base[i0 * 3 + 1], base[i1 * 3 + 1]}; \
    pz##j = (f2){base[i0 * 3 + 2], base[i1 * 3 + 2]}; \
    md##j = (f2){1e10f, 1e10f}; /* ref 1e10 exact */  \
    spts4[i0] = (f4){px##j.x, py##j.x, pz##j.x, 0.f}; \
    spts4[i1] = (f4){px##j.y, py##j.y, pz##j.y, 0.f}; \
  }
  FOR16(FPS_INIT)
#undef FPS_INIT

  // Pin coords in VGPRs (asm results can't be rematerialized from memory).
#define FPS_PIN(j) asm volatile("" : "+v"(px##j), "+v"(py##j), "+v"(pz##j));
  FOR16(FPS_PIN)
#undef FPS_PIN

  float cx = base[0], cy = base[1], cz = base[2];

  for (int s = 0; s < SEED_NUM; ++s) {
    if (tid == 0) {
      seedbuf[s * 3 + 0] = cx;
      seedbuf[s * 3 + 1] = cy;
      seedbuf[s * 3 + 2] = cz;
    }
    // pre-negated center: x + (-c) is IEEE-identical to x - c
    const f2 ncx = (f2){-cx, -cx}, ncy = (f2){-cy, -cy}, ncz = (f2){-cz, -cz};
    float bv = -1.0f;
    int bi = 0;
    // ascending index order + strict '>' keeps the first index on ties.
#define FPS_UPD(j)                                                      \
  {                                                                     \
    const f2 dx = pk_add(px##j, ncx);                                   \
    const f2 dy = pk_add(py##j, ncy);                                   \
    const f2 dz = pk_add(pz##j, ncz);                                   \
    const f2 t0 = pk_mul(dx, dx);                                       \
    const f2 t1 = pk_mul(dy, dy);                                       \
    const f2 t2 = pk_mul(dz, dz);                                       \
    const f2 d2 = pk_add(pk_add(t0, t1), t2);                           \
    const f2 m = __builtin_elementwise_min(md##j, d2);                  \
    md##j = m;                                                          \
    if (m.x > bv) { bv = m.x; bi = tid + (2 * (j)) * FPS_THREADS; }     \
    if (m.y > bv) { bv = m.y; bi = tid + (2 * (j) + 1) * FPS_THREADS; } \
  }
    FOR16(FPS_UPD)
#undef FPS_UPD
    // packed argmax key: bv >= 0 so f32 bits are monotone; u64 max ==
    // (max value, tie -> min index) == jnp.argmax semantics.
    unsigned long long key =
        ((unsigned long long)__float_as_uint(bv) << 32) |
        (unsigned long long)(unsigned)(N_PTS - 1 - bi);
    unsigned long long o;
    o = dpp_u64_bc1<0x111>(key);         key = (o > key) ? o : key;  // shr 1
    o = dpp_u64_bc1<0x112>(key);         key = (o > key) ? o : key;  // shr 2
    o = dpp_u64_bc1<0x114>(key);         key = (o > key) ? o : key;  // shr 4
    o = dpp_u64_bc1<0x118>(key);         key = (o > key) ? o : key;  // shr 8
    o = dpp_u64_keep<0x142, 0xa>(key);   key = (o > key) ? o : key;  // bcast15
    o = dpp_u64_keep<0x143, 0xc>(key);   key = (o > key) ? o : key;  // bcast31
    if (lane == 63) red[s & 1][wid] = key;
    __syncthreads();
    unsigned long long kmax = red[s & 1][0];
#pragma unroll
    for (int w = 1; w < 4; ++w) {
      const unsigned long long t = red[s & 1][w];
      kmax = (t > kmax) ? t : kmax;
    }
    const int ci = N_PTS - 1 - (int)(unsigned)(kmax & 0xffffffffull);
    const f4 c = spts4[ci];  // one ds_read_b128, same-address broadcast
    cx = c.x;
    cy = c.y;
    cz = c.z;
  }

  // bulk seed writeback (ordered by the final in-loop barrier)
  __syncthreads();
  float* sg = seeds + (size_t)b * SEED_NUM * 3;
  for (int i = tid; i < SEED_NUM * 3; i += FPS_THREADS) sg[i] = seedbuf[i];
}

// ---------------------------------------------------------------------------
// Kernel 2: one block per group, ALL 5 percentages at once.
// R13: (a) group points stored as f4 in LDS — KNN j-step is one
// ds_read_b128 (12 cy) instead of 3x ds_read_b32 (17.4 cy). (b) wsum[5][4]:
// per-p barriers removed (10 -> 1). (c) finalize fused into the LAST block
// (done-counter; __syncthreads drains vmcnt; threadfence + device-scope
// atomic reads make other blocks' sums visible) — one fewer launch.
// ---------------------------------------------------------------------------
__global__ __launch_bounds__(256) void group_kernel(
    const float* __restrict__ pcs, const float* __restrict__ seeds,
    double* __restrict__ totS /*[5]*/, double* __restrict__ accA /*[5][4]*/,
    unsigned int* __restrict__ dcnt, float* __restrict__ out) {
  const int g = blockIdx.x;  // 0 .. B*SEED_NUM-1
  const int b = g / SEED_NUM;
  const int tid = threadIdx.x;
  const int lane = tid & 63, wid = tid >> 6;

  const int Kc[5] = {65, 98, 131, 163, 196};
  const int off[5] = {0, 65, 163, 294, 457};
  const double Pd[5] = {0.004, 0.006, 0.008, 0.01, 0.012};
  float r2c[5], expnf[5], expdc[5];
#pragma unroll
  for (int p = 0; p < 5; ++p) {
    const double pd = Pd[p];
    const double rd = sqrt(pd);
    r2c[p] = (float)(rd * rd);                     // weak f32 cast of r*r
    const double expn_d = 8192.0 * pd;
    expnf[p] = (float)expn_d;
    expdc[p] = sqrtf((float)(M_PI / expn_d * pd));  // expect_dis (= sqrt(pi/N))
  }

  const float* base = pcs + (size_t)b * N_PTS * 3;
  const float* sp = seeds + (size_t)g * 3;
  const float sx = sp[0], sy = sp[1], sz = sp[2];

  __shared__ f4 lpt[LTOT];    // 10.4 KiB, one b128 per point
  __shared__ int cnt[5];
  __shared__ int wtot[4];     // fallback path only
  __shared__ double wsum[5][4];
  __shared__ int islast;

  if (tid < 5) cnt[tid] = 0;
  __syncthreads();

  // ---- single barrier-free scan: d2 once, append to each nested list ----
  const float r2max = r2c[4];
  for (int i = tid; i < N_PTS; i += 256) {
    const float x = base[i * 3 + 0];
    const float y = base[i * 3 + 1];
    const float z = base[i * 3 + 2];
    const float d2 = sqdist(x, y, z, sx, sy, sz);
    if (d2 < r2max) {
#pragma unroll
      for (int p = 0; p < 5; ++p) {
        if (d2 < r2c[p]) {
          const int pos = atomicAdd(&cnt[p], 1);
          if (pos < Kc[p]) {
            lpt[off[p] + pos] = (f4){x, y, z, 0.f};
          }
        }
      }
    }
  }
  __syncthreads();

  // ---- rare fallback: cnt>K needs the K smallest indices (ordered) ----
#pragma unroll
  for (int p = 0; p < 5; ++p) {
    if (cnt[p] > Kc[p]) {  // block-uniform (LDS value, post-barrier)
      int run = 0;
      for (int base_i = 0; base_i < N_PTS; base_i += 256) {
        const int i = base_i + tid;
        const float x = base[i * 3 + 0];
        const float y = base[i * 3 + 1];
        const float z = base[i * 3 + 2];
        const float d2 = sqdist(x, y, z, sx, sy, sz);
        const bool valid = d2 < r2c[p];
        const unsigned long long m = __ballot(valid);
        if (lane == 0) wtot[wid] = __popcll(m);
        __syncthreads();
        int pos = run + __popcll(m & ((1ull << lane) - 1ull));
        for (int w = 0; w < wid; ++w) pos += wtot[w];
        if (valid && pos < Kc[p]) {
          lpt[off[p] + pos] = (f4){x, y, z, 0.f};
        }
        run += wtot[0] + wtot[1] + wtot[2] + wtot[3];
        __syncthreads();
      }
    }
  }

  // ---- KNN + clutter per percentage: 4 threads/row, shfl two-min merge.
  //      No barriers inside the p-loop (lpt/cnt are read-only here; wsum is
  //      per-p slotted). ----
#pragma unroll
  for (int p = 0; p < 5; ++p) {
    const int gn = min(cnt[p], Kc[p]);  // gnum >= 1 (seed itself is in pcs)
    const float ed = expdc[p];
    const int lb = off[p];
    double localS = 0.0;
    for (int r0 = 0; r0 < gn; r0 += 64) {
      const int row = r0 + (tid >> 2);
      const int sub = tid & 3;
      float m1 = INFINITY, m2 = INFINITY;
      if (row < gn) {
        const f4 pi = lpt[lb + row];
        for (int j = sub; j < gn; j += 4) {
          const f4 pj = lpt[lb + j];
          const float d2 = sqdist(pi.x, pi.y, pi.z, pj.x, pj.y, pj.z);
          if (d2 < m1) { m2 = m1; m1 = d2; }
          else if (d2 < m2) { m2 = d2; }
        }
      }
      // merge (m1,m2) pairs across the 4 sub-lanes (multiset two-min)
#pragma unroll
      for (int d = 1; d <= 2; d <<= 1) {
        const float om1 = __shfl_xor(m1, d);
        const float om2 = __shfl_xor(m2, d);
        const float lo = fminf(m1, om1);
        const float hi = fmaxf(m1, om1);
        m2 = fminf(fminf(m2, om2), hi);
        m1 = lo;
      }
      if (row < gn && sub == 0) {
        const float nn2 = (m2 > 1e37f) ? 0.0f : m2;  // inf (gn==1) -> 0
        const float nnd = (nn2 > 0.0f) ? sqrtf(nn2) : 0.0f;
        const float diff = __fsub_rn(nnd, ed);
        const float clut = __fdiv_rn(__fmul_rn(diff, diff),
                                     __fadd_rn(ed, 1e-12f));
        localS += (double)clut;
      }
    }
#pragma unroll
    for (int o = 32; o > 0; o >>= 1) localS += __shfl_down(localS, o);
    if (lane == 0) wsum[p][wid] = localS;
  }
  __syncthreads();

  // 10 parallel device atomics: threads 0-4 -> totS, threads 5-9 -> accA.
  if (tid < 5) {
    const double S = wsum[tid][0] + wsum[tid][1] + wsum[tid][2] + wsum[tid][3];
    atomicAdd(&totS[tid], S);
  } else if (tid < 10) {
    const int p = tid - 5;
    const int gn = min(cnt[p], Kc[p]);
    const float gf = (float)gn;
    const float dd = __fsub_rn(gf, expnf[p]);
    const float imb = __fdiv_rn(__fmul_rn(dd, dd), expnf[p]);
    atomicAdd(&accA[p * 4 + b], (double)imb / (double)gf);
  }

  // ---- fused finalize: last block computes the loss ----
  __syncthreads();  // drains vmcnt -> this block's atomics are at L2
  if (tid == 0) {
    __threadfence();
    const unsigned int old = atomicAdd(dcnt, 1u);
    islast = (old == (unsigned int)(N_GROUPS - 1)) ? 1 : 0;
  }
  __syncthreads();
  if (islast) {
    __shared__ double fin[25];
    if (tid < 25) {
      // device-scope atomic read (add 0.0) -> sees all blocks' additions
      const double* src = (tid < 5) ? &totS[tid] : &accA[tid - 5];
      fin[tid] = atomicAdd((double*)src, 0.0);
    }
    __syncthreads();
    if (tid < B_SZ) {
      double acc = 0.0;
#pragma unroll
      for (int p = 0; p < 5; ++p)
        acc += fin[p] * (fin[5 + p * 4 + tid] / (double)SEED_NUM);
      out[tid] = (float)(acc / 5.0);
    }
  }
}

extern "C" void kernel_launch(void* const* d_in, const int* in_sizes, int n_in,
                              void* d_out, int out_size, void* d_ws,
                              size_t ws_size, hipStream_t stream) {
  (void)in_sizes; (void)n_in; (void)out_size; (void)ws_size;
  const float* pcs = (const float*)d_in[0];
  float* out = (float*)d_out;

  // ws layout: seeds (B*409*3 f32 = 19632 B, 8-aligned), then 26 doubles:
  // totS[5], accA[20], done-counter.
  float* seeds = (float*)d_ws;
  double* sums = (double*)((char*)d_ws + 19632);

  fps_kernel<<<B_SZ, FPS_THREADS, 0, stream>>>(pcs, seeds, sums);
  group_kernel<<<N_GROUPS, 256, 0, stream>>>(
      pcs, seeds, sums, sums + 5, (unsigned int*)(sums + 25), out);
}

// Round 5
// 433.014 us; speedup vs baseline: 1.1931x; 1.1931x over previous
//
#include <hip/hip_runtime.h>
#include <math.h>

#define N_PTS 8192
#define B_SZ 4
#define SEED_NUM 409
#define FPS_THREADS 256  // 4 waves, 1 per SIMD
#define LTOT 653  // 65+98+131+163+196
#define N_GROUPS (B_SZ * SEED_NUM)

typedef float f2 __attribute__((ext_vector_type(2)));
typedef float f4 __attribute__((ext_vector_type(4)));

// Exact IEEE f32 squared distance, same op order as the reference:
// ((dx*dx + dy*dy) + dz*dz), no FMA contraction.
__device__ __forceinline__ float sqdist(float ax, float ay, float az,
                                        float bx, float by, float bz) {
  float dx = __fsub_rn(ax, bx);
  float dy = __fsub_rn(ay, by);
  float dz = __fsub_rn(az, bz);
  return __fadd_rn(__fadd_rn(__fmul_rn(dx, dx), __fmul_rn(dy, dy)),
                   __fmul_rn(dz, dz));
}

#define FOR16(M) \
  M(0) M(1) M(2) M(3) M(4) M(5) M(6) M(7) \
  M(8) M(9) M(10) M(11) M(12) M(13) M(14) M(15)

// u64 lane-move via two 32-bit DPP ops (ctrl fields must be constant
// expressions -> template params). shr-stages: bound_ctrl=1 (OOB lanes
// read 0 — harmless for max of non-negative keys). bcast stages keep `old`
// in masked-off rows so the subsequent max is a no-op there.
template <int CTRL>
__device__ __forceinline__ unsigned long long dpp_u64_bc1(
    unsigned long long k) {
  const unsigned lo2 = (unsigned)__builtin_amdgcn_update_dpp(
      0, (int)(unsigned)k, CTRL, 0xf, 0xf, true);
  const unsigned hi2 = (unsigned)__builtin_amdgcn_update_dpp(
      0, (int)(unsigned)(k >> 32), CTRL, 0xf, 0xf, true);
  return ((unsigned long long)hi2 << 32) | lo2;
}
template <int CTRL, int ROW_MASK>
__device__ __forceinline__ unsigned long long dpp_u64_keep(
    unsigned long long k) {
  const unsigned lo2 = (unsigned)__builtin_amdgcn_update_dpp(
      (int)(unsigned)k, (int)(unsigned)k, CTRL, ROW_MASK, 0xf, false);
  const unsigned hi2 = (unsigned)__builtin_amdgcn_update_dpp(
      (int)(unsigned)(k >> 32), (int)(unsigned)(k >> 32), CTRL, ROW_MASK, 0xf,
      false);
  return ((unsigned long long)hi2 << 32) | lo2;
}

// ---------------------------------------------------------------------------
// Kernel 1: farthest point sampling. One block per batch (4 blocks).
// R15: VERBATIM revert to the R10 loop (326.8 us proven). Evidence ledger on
// this loop: R11 scratch-tree +2.3x; R12 reg-tree +73cy; R13 ulonglong2 tail
// +41cy; R14 forced-pk asm +420cy. Every deviation from this text regressed —
// the compiler's own schedule of the f2 ops + running argmax is the local
// optimum. DO NOT perturb without .s-level evidence.
// (R10: 4 waves, 32 pts/thread in f2 pairs, f4 winner broadcast.
//  R8: packed f32. R6: DPP argmax reduce. R4: asm "+v" pin.)
// ---------------------------------------------------------------------------
__global__ __launch_bounds__(FPS_THREADS, 1) void fps_kernel(
    const float* __restrict__ pcs, float* __restrict__ seeds,
    double* __restrict__ sums /*26 doubles: totS[5]+accA[20]+donecnt*/) {
#pragma clang fp contract(off)
  const int b = blockIdx.x;
  const int tid = threadIdx.x;
  const int lane = tid & 63, wid = tid >> 6;  // 4 waves
  const float* base = pcs + (size_t)b * N_PTS * 3;

  if (b == 0 && tid < 26) sums[tid] = 0.0;  // zero totS[5]+accA[20]+donecnt

  __shared__ f4 spts4[N_PTS];              // 128 KiB: winner-coord broadcast
  __shared__ float seedbuf[SEED_NUM * 3];  // 4.8 KiB: deferred seed output
  __shared__ unsigned long long red[2][4];

  // pair j holds points i0 = tid + (2j)*256 and i1 = tid + (2j+1)*256
#define FPS_DECL(j) f2 px##j, py##j, pz##j, md##j;
  FOR16(FPS_DECL)
#undef FPS_DECL

#define FPS_INIT(j)                                   \
  {                                                   \
    const int i0 = tid + (2 * (j)) * FPS_THREADS;     \
    const int i1 = i0 + FPS_THREADS;                  \
    px##j = (f2){base[i0 * 3 + 0], base[i1 * 3 + 0]}; \
    py##j = (f2){base[i0 * 3 + 1], base[i1 * 3 + 1]}; \
    pz##j = (f2){base[i0 * 3 + 2], base[i1 * 3 + 2]}; \
    md##j = (f2){1e10f, 1e10f}; /* ref 1e10 exact */  \
    spts4[i0] = (f4){px##j.x, py##j.x, pz##j.x, 0.f}; \
    spts4[i1] = (f4){px##j.y, py##j.y, pz##j.y, 0.f}; \
  }
  FOR16(FPS_INIT)
#undef FPS_INIT

  // Pin coords in VGPRs (asm results can't be rematerialized from memory).
#define FPS_PIN(j) asm volatile("" : "+v"(px##j), "+v"(py##j), "+v"(pz##j));
  FOR16(FPS_PIN)
#undef FPS_PIN

  float cx = base[0], cy = base[1], cz = base[2];

  for (int s = 0; s < SEED_NUM; ++s) {
    if (tid == 0) {
      seedbuf[s * 3 + 0] = cx;
      seedbuf[s * 3 + 1] = cy;
      seedbuf[s * 3 + 2] = cz;
    }
    const f2 ccx = (f2){cx, cx}, ccy = (f2){cy, cy}, ccz = (f2){cz, cz};
    float bv = -1.0f;
    int bi = 0;
    // ascending index order + strict '>' keeps the first index on ties.
#define FPS_UPD(j)                                                      \
  {                                                                     \
    const f2 dx = px##j - ccx;                                          \
    const f2 dy = py##j - ccy;                                          \
    const f2 dz = pz##j - ccz;                                          \
    const f2 t0 = dx * dx;                                              \
    const f2 t1 = dy * dy;                                              \
    const f2 t2 = dz * dz;                                              \
    const f2 d2 = (t0 + t1) + t2;                                       \
    const f2 m = __builtin_elementwise_min(md##j, d2);                  \
    md##j = m;                                                          \
    if (m.x > bv) { bv = m.x; bi = tid + (2 * (j)) * FPS_THREADS; }     \
    if (m.y > bv) { bv = m.y; bi = tid + (2 * (j) + 1) * FPS_THREADS; } \
  }
    FOR16(FPS_UPD)
#undef FPS_UPD
    // packed argmax key: bv >= 0 so f32 bits are monotone; u64 max ==
    // (max value, tie -> min index) == jnp.argmax semantics.
    unsigned long long key =
        ((unsigned long long)__float_as_uint(bv) << 32) |
        (unsigned long long)(unsigned)(N_PTS - 1 - bi);
    unsigned long long o;
    o = dpp_u64_bc1<0x111>(key);         key = (o > key) ? o : key;  // shr 1
    o = dpp_u64_bc1<0x112>(key);         key = (o > key) ? o : key;  // shr 2
    o = dpp_u64_bc1<0x114>(key);         key = (o > key) ? o : key;  // shr 4
    o = dpp_u64_bc1<0x118>(key);         key = (o > key) ? o : key;  // shr 8
    o = dpp_u64_keep<0x142, 0xa>(key);   key = (o > key) ? o : key;  // bcast15
    o = dpp_u64_keep<0x143, 0xc>(key);   key = (o > key) ? o : key;  // bcast31
    if (lane == 63) red[s & 1][wid] = key;
    __syncthreads();
    unsigned long long kmax = red[s & 1][0];
#pragma unroll
    for (int w = 1; w < 4; ++w) {
      const unsigned long long t = red[s & 1][w];
      kmax = (t > kmax) ? t : kmax;
    }
    const int ci = N_PTS - 1 - (int)(unsigned)(kmax & 0xffffffffull);
    const f4 c = spts4[ci];  // one ds_read_b128, same-address broadcast
    cx = c.x;
    cy = c.y;
    cz = c.z;
  }

  // bulk seed writeback (ordered by the final in-loop barrier)
  __syncthreads();
  float* sg = seeds + (size_t)b * SEED_NUM * 3;
  for (int i = tid; i < SEED_NUM * 3; i += FPS_THREADS) sg[i] = seedbuf[i];
}

// ---------------------------------------------------------------------------
// Kernel 2: one block per group, ALL 5 percentages at once.
// R15: the 5 valid-lists are NESTED (r2c ascending), so store each point ONCE
// in a tier bucket (tier = smallest p containing it); list_p = prefix
// [0, ccum[p]) of the bucket-ordered array. One segmented pass per row with
// snapshot-merges at bucket boundaries yields all 5 second-mins: pair reads
// drop from sum(gn_p^2)~96K to gn_4^2~38K ds_read_b128 per block (the
// dominant non-fps cost). Scan pass vectorized: 3x f4 loads per 4 points
// (24 coalesced instrs vs 96 scalar). Capped lists (cnt>K, measure-zero) ->
// full old-style ordered fallback for all p.
// (R13: f4 LDS points; single barrier; fused finalize via done-counter.)
// ---------------------------------------------------------------------------
__global__ __launch_bounds__(256) void group_kernel(
    const float* __restrict__ pcs, const float* __restrict__ seeds,
    double* __restrict__ totS /*[5]*/, double* __restrict__ accA /*[5][4]*/,
    unsigned int* __restrict__ dcnt, float* __restrict__ out) {
  const int g = blockIdx.x;  // 0 .. B*SEED_NUM-1
  const int b = g / SEED_NUM;
  const int tid = threadIdx.x;
  const int lane = tid & 63, wid = tid >> 6;

  const int Kc[5] = {65, 98, 131, 163, 196};
  const int off[5] = {0, 65, 163, 294, 457};  // fallback layout only
  const double Pd[5] = {0.004, 0.006, 0.008, 0.01, 0.012};
  float r2c[5], expnf[5], expdc[5];
#pragma unroll
  for (int p = 0; p < 5; ++p) {
    const double pd = Pd[p];
    const double rd = sqrt(pd);
    r2c[p] = (float)(rd * rd);                     // weak f32 cast of r*r
    const double expn_d = 8192.0 * pd;
    expnf[p] = (float)expn_d;
    expdc[p] = sqrtf((float)(M_PI / expn_d * pd));  // expect_dis (= sqrt(pi/N))
  }

  const float* base = pcs + (size_t)b * N_PTS * 3;
  const float* sp = seeds + (size_t)g * 3;
  const float sx = sp[0], sy = sp[1], sz = sp[2];

  __shared__ f4 tmp[LTOT];    // pass-1 survivors (x,y,z,tier)
  __shared__ f4 lpt[LTOT];    // bucket-ordered points (x,y,z,0)
  __shared__ int tcnt[5], tbase[5], bcnt[5], ccum[5];
  __shared__ int ntmp, capped;
  __shared__ int wtot[4];     // fallback path only
  __shared__ double wsum[5][4];
  __shared__ int islast;

  if (tid < 5) { tcnt[tid] = 0; bcnt[tid] = 0; }
  if (tid == 0) ntmp = 0;
  __syncthreads();

  // ---- pass 1: vectorized scan, tier-count + unordered survivor append ----
  const float r2max = r2c[4];
  const f4* base4 = (const f4*)base;  // 12B-packed points, 16B-aligned base
#define PROC(X, Y, Z)                                                       \
  {                                                                         \
    const float d2 = sqdist((X), (Y), (Z), sx, sy, sz);                     \
    if (d2 < r2max) {                                                       \
      const int tier = (d2 < r2c[0]) ? 0                                    \
                       : (d2 < r2c[1]) ? 1                                  \
                       : (d2 < r2c[2]) ? 2                                  \
                       : (d2 < r2c[3]) ? 3 : 4;                             \
      atomicAdd(&tcnt[tier], 1);                                            \
      const int pos = atomicAdd(&ntmp, 1);                                  \
      if (pos < LTOT) tmp[pos] = (f4){(X), (Y), (Z), (float)tier};          \
    }                                                                       \
  }
  for (int it = 0; it < 8; ++it) {
    const int q = it * 256 + tid;  // quad-of-points index, 0..2047
    const f4 v0 = base4[q * 3 + 0];
    const f4 v1 = base4[q * 3 + 1];
    const f4 v2 = base4[q * 3 + 2];
    PROC(v0.x, v0.y, v0.z)
    PROC(v0.w, v1.x, v1.y)
    PROC(v1.z, v1.w, v2.x)
    PROC(v2.y, v2.z, v2.w)
  }
#undef PROC
  __syncthreads();

  // ---- prefix + cap check (ntmp == ccum[4]; ccum[4]>LTOT implies capped) ----
  if (tid == 0) {
    int acc = 0, cap = 0;
#pragma unroll
    for (int t = 0; t < 5; ++t) {
      tbase[t] = acc;
      acc += tcnt[t];
      ccum[t] = acc;
    }
#pragma unroll
    for (int p = 0; p < 5; ++p) cap |= (ccum[p] > Kc[p]) ? 1 : 0;
    capped = cap;
  }
  __syncthreads();

  // ---- pass 2: scatter survivors to tier-bucket positions ----
  const int nt = min(ntmp, LTOT);
  for (int t = tid; t < nt; t += 256) {
    const f4 e = tmp[t];
    const int tier = (int)e.w;
    const int pos = tbase[tier] + atomicAdd(&bcnt[tier], 1);
    if (pos < LTOT) lpt[pos] = (f4){e.x, e.y, e.z, 0.f};
  }
  __syncthreads();

  if (!capped) {
    // ---- segmented KNN: one pass over [0, c4) per row, snapshots at
    //      bucket boundaries give the two-min of every prefix list ----
    const int c0 = ccum[0], c1 = ccum[1], c2 = ccum[2], c3 = ccum[3],
              c4 = ccum[4];
    double lS0 = 0.0, lS1 = 0.0, lS2 = 0.0, lS3 = 0.0, lS4 = 0.0;
    for (int r0 = 0; r0 < c4; r0 += 64) {
      const int row = r0 + (tid >> 2);
      const int sub = tid & 3;
      const bool rok = row < c4;
      const f4 pi = lpt[rok ? row : 0];
      float m1 = INFINITY, m2 = INFINITY;
      int j = sub;
#define SEGMENT(CP, EDP, LSP)                                               \
  {                                                                         \
    for (; j < (CP); j += 4) {                                              \
      const f4 pj = lpt[j];                                                 \
      const float d2 = sqdist(pi.x, pi.y, pi.z, pj.x, pj.y, pj.z);          \
      if (d2 < m1) { m2 = m1; m1 = d2; }                                    \
      else if (d2 < m2) { m2 = d2; }                                        \
    }                                                                       \
    /* snapshot-merge (m1,m2) over the 4 sub-lanes; running pair kept */    \
    float s1 = m1, s2 = m2;                                                 \
    {                                                                       \
      const float o1 = __shfl_xor(s1, 1), o2 = __shfl_xor(s2, 1);           \
      const float lo = fminf(s1, o1), hi = fmaxf(s1, o1);                   \
      s2 = fminf(fminf(s2, o2), hi); s1 = lo;                               \
    }                                                                       \
    {                                                                       \
      const float o1 = __shfl_xor(s1, 2), o2 = __shfl_xor(s2, 2);           \
      const float lo = fminf(s1, o1), hi = fmaxf(s1, o1);                   \
      s2 = fminf(fminf(s2, o2), hi); s1 = lo;                               \
    }                                                                       \
    if (rok && sub == 0 && row < (CP)) {                                    \
      const float nn2 = (s2 > 1e37f) ? 0.0f : s2; /* inf -> 0 */            \
      const float nnd = (nn2 > 0.0f) ? sqrtf(nn2) : 0.0f;                   \
      const float diff = __fsub_rn(nnd, (EDP));                             \
      const float clut = __fdiv_rn(__fmul_rn(diff, diff),                   \
                                   __fadd_rn((EDP), 1e-12f));               \
      LSP += (double)clut;                                                  \
    }                                                                       \
  }
      SEGMENT(c0, expdc[0], lS0)
      SEGMENT(c1, expdc[1], lS1)
      SEGMENT(c2, expdc[2], lS2)
      SEGMENT(c3, expdc[3], lS3)
      SEGMENT(c4, expdc[4], lS4)
#undef SEGMENT
    }
#define RED(LSP, P)                                          \
  {                                                          \
    double v = (LSP);                                        \
    for (int o = 32; o > 0; o >>= 1) v += __shfl_down(v, o); \
    if (lane == 0) wsum[(P)][wid] = v;                       \
  }
    RED(lS0, 0) RED(lS1, 1) RED(lS2, 2) RED(lS3, 3) RED(lS4, 4)
#undef RED
  } else {
    // ---- measure-zero fallback: ordered per-p lists (old layout) + old
    //      per-p KNN. Correct for cnt>K (first-K-original-order semantics).
#pragma unroll
    for (int p = 0; p < 5; ++p) {
      int run = 0;
      for (int base_i = 0; base_i < N_PTS; base_i += 256) {
        const int i = base_i + tid;
        const float x = base[i * 3 + 0];
        const float y = base[i * 3 + 1];
        const float z = base[i * 3 + 2];
        const float d2 = sqdist(x, y, z, sx, sy, sz);
        const bool valid = d2 < r2c[p];
        const unsigned long long m = __ballot(valid);
        if (lane == 0) wtot[wid] = __popcll(m);
        __syncthreads();
        int pos = run + __popcll(m & ((1ull << lane) - 1ull));
        for (int w = 0; w < wid; ++w) pos += wtot[w];
        if (valid && pos < Kc[p]) {
          lpt[off[p] + pos] = (f4){x, y, z, 0.f};
        }
        run += wtot[0] + wtot[1] + wtot[2] + wtot[3];
        __syncthreads();
      }
    }
#pragma unroll
    for (int p = 0; p < 5; ++p) {
      const int gn = min(ccum[p], Kc[p]);
      const float ed = expdc[p];
      const int lb = off[p];
      double localS = 0.0;
      for (int r0 = 0; r0 < gn; r0 += 64) {
        const int row = r0 + (tid >> 2);
        const int sub = tid & 3;
        float m1 = INFINITY, m2 = INFINITY;
        if (row < gn) {
          const f4 pi = lpt[lb + row];
          for (int j = sub; j < gn; j += 4) {
            const f4 pj = lpt[lb + j];
            const float d2 = sqdist(pi.x, pi.y, pi.z, pj.x, pj.y, pj.z);
            if (d2 < m1) { m2 = m1; m1 = d2; }
            else if (d2 < m2) { m2 = d2; }
          }
        }
#pragma unroll
        for (int d = 1; d <= 2; d <<= 1) {
          const float om1 = __shfl_xor(m1, d);
          const float om2 = __shfl_xor(m2, d);
          const float lo = fminf(m1, om1);
          const float hi = fmaxf(m1, om1);
          m2 = fminf(fminf(m2, om2), hi);
          m1 = lo;
        }
        if (row < gn && sub == 0) {
          const float nn2 = (m2 > 1e37f) ? 0.0f : m2;
          const float nnd = (nn2 > 0.0f) ? sqrtf(nn2) : 0.0f;
          const float diff = __fsub_rn(nnd, ed);
          const float clut = __fdiv_rn(__fmul_rn(diff, diff),
                                       __fadd_rn(ed, 1e-12f));
          localS += (double)clut;
        }
      }
#pragma unroll
      for (int o = 32; o > 0; o >>= 1) localS += __shfl_down(localS, o);
      if (lane == 0) wsum[p][wid] = localS;
      __syncthreads();
    }
  }
  __syncthreads();

  // 10 parallel device atomics: threads 0-4 -> totS, threads 5-9 -> accA.
  if (tid < 5) {
    const double S = wsum[tid][0] + wsum[tid][1] + wsum[tid][2] + wsum[tid][3];
    atomicAdd(&totS[tid], S);
  } else if (tid < 10) {
    const int p = tid - 5;
    const int gn = min(ccum[p], Kc[p]);
    const float gf = (float)gn;
    const float dd = __fsub_rn(gf, expnf[p]);
    const float imb = __fdiv_rn(__fmul_rn(dd, dd), expnf[p]);
    atomicAdd(&accA[p * 4 + b], (double)imb / (double)gf);
  }

  // ---- fused finalize: last block computes the loss ----
  __syncthreads();  // drains vmcnt -> this block's atomics are at L2
  if (tid == 0) {
    __threadfence();
    const unsigned int old = atomicAdd(dcnt, 1u);
    islast = (old == (unsigned int)(N_GROUPS - 1)) ? 1 : 0;
  }
  __syncthreads();
  if (islast) {
    __shared__ double fin[25];
    if (tid < 25) {
      // device-scope atomic read (add 0.0) -> sees all blocks' additions
      const double* src = (tid < 5) ? &totS[tid] : &accA[tid - 5];
      fin[tid] = atomicAdd((double*)src, 0.0);
    }
    __syncthreads();
    if (tid < B_SZ) {
      double acc = 0.0;
#pragma unroll
      for (int p = 0; p < 5; ++p)
        acc += fin[p] * (fin[5 + p * 4 + tid] / (double)SEED_NUM);
      out[tid] = (float)(acc / 5.0);
    }
  }
}

extern "C" void kernel_launch(void* const* d_in, const int* in_sizes, int n_in,
                              void* d_out, int out_size, void* d_ws,
                              size_t ws_size, hipStream_t stream) {
  (void)in_sizes; (void)n_in; (void)out_size; (void)ws_size;
  const float* pcs = (const float*)d_in[0];
  float* out = (float*)d_out;

  // ws layout: seeds (B*409*3 f32 = 19632 B, 8-aligned), then 26 doubles:
  // totS[5], accA[20], done-counter.
  float* seeds = (float*)d_ws;
  double* sums = (double*)((char*)d_ws + 19632);

  fps_kernel<<<B_SZ, FPS_THREADS, 0, stream>>>(pcs, seeds, sums);
  group_kernel<<<N_GROUPS, 256, 0, stream>>>(
      pcs, seeds, sums, sums + 5, (unsigned int*)(sums + 25), out);
}